// Round 11
// baseline (1503.562 us; speedup 1.0000x reference)
//
#include <hip/hip_runtime.h>
#include <stdint.h>
#include <stddef.h>

// ---------------------------------------------------------------------------
// Sparse top-2 MoE, bf16 MFMA, fp32 accumulate.
//   convert: w1/w3/w2 fp32 -> bf16, tile-panel layout [e][p][q][128x64],
//            XOR-swizzled (chunk cs holds logical col cs^(r&7))  [proven r2]
//   router:  logits -> softmax -> top2 -> per-expert lists, idx packed t*2+rank
//   GU:      h = silu(x@w1^T) * (x@w3^T)   [byte-exact r2 structure, 625us]
//   Y:       ybuf[rank][tok] = coef*(h@w2^T)  plain stores; 64x256 tiles,
//            8 panels (hbuf re-read 1.07GB), LDS 40.8KB forces EXACTLY
//            3 blocks/CU (768 slots; 2112 blocks -> 92% batch efficiency
//            vs Y5's 71%), acc=64 AGPR + VGPR<=106 -> 3 waves/SIMD.
//   merge:   out = ybuf0 + ybuf1
// nt-major dispatch: co-resident blocks share the weight panel (L2-hot).
// ws layout (MiB): [0,1) lists | [1,33) xb | [33,161) w1b (later w2b)
//                  [161,289) w3b (later ybuf[2]) | [289,418) hbuf
// ---------------------------------------------------------------------------

constexpr int kTokens  = 8192;
constexpr int kHidden  = 2048;
constexpr int kInter   = 4096;
constexpr int kExperts = 8;

constexpr int BM = 128, BN = 128, BK = 64;
constexpr int MAX_MT = (2 * kTokens) / BM + kExperts;   // 136
constexpr int BM7 = 64;                                  // Y7 tile rows
constexpr int MAX_MT7 = (2 * kTokens) / BM7 + kExperts;  // 264
constexpr int NTY = kInter / BK;                         // 64 K-tiles (Y)
constexpr int kSlotCap = 16512;                          // hbuf rows incl. slack

typedef short bf16x8 __attribute__((ext_vector_type(8)));
typedef float f32x4  __attribute__((ext_vector_type(4)));
typedef unsigned int u32;

__device__ __forceinline__ unsigned short f2bf(float f) {
  union { float f; unsigned u; } v; v.f = f;
  unsigned r = v.u + 0x7FFFu + ((v.u >> 16) & 1u);  // RTNE
  return (unsigned short)(r >> 16);
}

__device__ __forceinline__ void gload16(const void* g, void* l) {
  __builtin_amdgcn_global_load_lds(
      (const __attribute__((address_space(1))) u32*)g,
      (__attribute__((address_space(3))) u32*)l, 16, 0, 0);
}

// ---------------------------- weight convert (proven r2) --------------------
__global__ __launch_bounds__(256) void convert_w(
    const float* __restrict__ src, unsigned short* __restrict__ dst,
    int lp, int lq, int K, long nchunks)
{
  long stride = (long)gridDim.x * blockDim.x;
  for (long g = blockIdx.x * (long)blockDim.x + threadIdx.x; g < nchunks; g += stride) {
    int  l   = (int)(g & 1023);
    long blk = g >> 10;
    int  q   = (int)(blk & ((1 << lq) - 1));
    long ep  = blk >> lq;
    int  p   = (int)(ep & ((1 << lp) - 1));
    int  e   = (int)(ep >> lp);
    int r = l >> 3, cs = l & 7, c = cs ^ (r & 7);
    size_t soff = (((size_t)(e << lp) + p) * 128 + r) * (size_t)K + (size_t)q * 64 + c * 8;
    float4 v0 = *reinterpret_cast<const float4*>(src + soff);
    float4 v1 = *reinterpret_cast<const float4*>(src + soff + 4);
    uint4 o;
    o.x = (u32)f2bf(v0.x) | ((u32)f2bf(v0.y) << 16);
    o.y = (u32)f2bf(v0.z) | ((u32)f2bf(v0.w) << 16);
    o.z = (u32)f2bf(v1.x) | ((u32)f2bf(v1.y) << 16);
    o.w = (u32)f2bf(v1.z) | ((u32)f2bf(v1.w) << 16);
    *reinterpret_cast<uint4*>(dst + g * 8) = o;
  }
}

// ---------------------------- router (idx packed t*2+rank) ------------------
__global__ __launch_bounds__(256) void moe_router(
    const float* __restrict__ x, const float* __restrict__ gate_w,
    unsigned short* __restrict__ xb, int* __restrict__ counts,
    int* __restrict__ list_idx, float* __restrict__ list_w)
{
  const int lane = threadIdx.x & 63;
  const int wave = threadIdx.x >> 6;
  const int t = blockIdx.x * 4 + wave;

  float acc[kExperts];
#pragma unroll
  for (int e = 0; e < kExperts; ++e) acc[e] = 0.f;

  const float4* xrow = reinterpret_cast<const float4*>(x + (size_t)t * kHidden);
#pragma unroll
  for (int j = 0; j < 8; ++j) {
    float4 xv = xrow[j * 64 + lane];
    uint2 pk;
    pk.x = (u32)f2bf(xv.x) | ((u32)f2bf(xv.y) << 16);
    pk.y = (u32)f2bf(xv.z) | ((u32)f2bf(xv.w) << 16);
    *reinterpret_cast<uint2*>(xb + (size_t)t * kHidden + j * 256 + lane * 4) = pk;
#pragma unroll
    for (int e = 0; e < kExperts; ++e) {
      float4 gv = reinterpret_cast<const float4*>(gate_w + (size_t)e * kHidden)[j * 64 + lane];
      acc[e] += xv.x * gv.x + xv.y * gv.y + xv.z * gv.z + xv.w * gv.w;
    }
  }
#pragma unroll
  for (int e = 0; e < kExperts; ++e) {
#pragma unroll
    for (int m = 32; m >= 1; m >>= 1) acc[e] += __shfl_xor(acc[e], m);
  }
  if (lane == 0) {
    float mx = acc[0];
#pragma unroll
    for (int e = 1; e < kExperts; ++e) mx = fmaxf(mx, acc[e]);
    float p[kExperts]; float s = 0.f;
#pragma unroll
    for (int e = 0; e < kExperts; ++e) { p[e] = __expf(acc[e] - mx); s += p[e]; }
    float inv = 1.f / s;
    int i1 = 0; float v1 = p[0];
#pragma unroll
    for (int e = 1; e < kExperts; ++e) if (p[e] > v1) { v1 = p[e]; i1 = e; }
    int i2 = (i1 == 0) ? 1 : 0; float v2 = p[i2];
#pragma unroll
    for (int e = 0; e < kExperts; ++e) {
      if (e == i1 || e == i2) continue;
      if (p[e] > v2) { v2 = p[e]; i2 = e; }
    }
    int s1 = atomicAdd(&counts[i1], 1);
    list_idx[i1 * kTokens + s1] = t * 2 + 0;
    list_w [i1 * kTokens + s1] = v1 * inv;
    int s2 = atomicAdd(&counts[i2], 1);
    list_idx[i2 * kTokens + s2] = t * 2 + 1;
    list_w [i2 * kTokens + s2] = v2 * inv;
  }
}

// ------------------- tile mapping helpers -------------------
__device__ __forceinline__ bool map_tile(const int* __restrict__ counts, int mt,
                                         int& e, int& lm, int& sb, int& ne)
{
  int tb = 0; sb = 0;
  for (e = 0; e < kExperts; ++e) {
    ne = counts[e];
    int tiles = (ne + BM - 1) / BM;
    if (mt < tb + tiles) { lm = mt - tb; return true; }
    tb += tiles; sb += ne;
  }
  return false;
}

__device__ __forceinline__ bool map_tile7(const int* __restrict__ counts, int mt,
                                          int& e, int& lm, int& sb, int& ne)
{
  int tb = 0; sb = 0;
  for (e = 0; e < kExperts; ++e) {
    ne = counts[e];
    int tiles = (ne + BM7 - 1) / BM7;
    if (mt < tb + tiles) { lm = mt - tb; return true; }
    tb += tiles; sb += ne;
  }
  return false;
}

// ---------------------------- GU GEMM (byte-exact r2, 625us) ----------------
__global__ __launch_bounds__(256, 2) void moe_gu(
    const unsigned short* __restrict__ xb,
    const unsigned short* __restrict__ w1b, const unsigned short* __restrict__ w3b,
    const int* __restrict__ counts, const int* __restrict__ list_idx,
    unsigned short* __restrict__ hbuf)
{
  __shared__ unsigned short As [BM * BK];
  __shared__ unsigned short B1s[BN * BK];
  __shared__ unsigned short B3s[BN * BK];
  __shared__ int toks[BM];

  const int tid = threadIdx.x;
  const int nt  = blockIdx.x / MAX_MT;
  const int mt  = blockIdx.x % MAX_MT;

  int e, lm, sb, ne;
  if (!map_tile(counts, mt, e, lm, sb, ne)) return;
  const int row0 = lm * BM;

  if (tid < BM) {
    int lr = row0 + tid;
    toks[tid] = list_idx[e * kTokens + ((lr < ne) ? lr : 0)] >> 1;
  }
  __syncthreads();

  const int lane = tid & 63;
  const int w = tid >> 6;
  const int wr = w >> 1, wc = w & 1;

  const unsigned short* srcA[4];
  const unsigned short* srcB1[4];
  const unsigned short* srcB3[4];
  const size_t bbase = ((size_t)(e * (kInter / BN) + nt) * (kHidden / BK)) * 1024;
#pragma unroll
  for (int i = 0; i < 4; ++i) {
    int l = (w * 4 + i) * 64 + lane;
    int r = l >> 3, cs = l & 7, c = cs ^ (r & 7);
    srcA[i]  = xb  + (size_t)toks[r] * kHidden + c * 8;
    srcB1[i] = w1b + (bbase + l) * 8;
    srcB3[i] = w3b + (bbase + l) * 8;
  }

  f32x4 accG[4][4], accU[4][4];
  const f32x4 zero = {0.f, 0.f, 0.f, 0.f};
#pragma unroll
  for (int m = 0; m < 4; ++m)
#pragma unroll
    for (int n = 0; n < 4; ++n) { accG[m][n] = zero; accU[m][n] = zero; }

  for (int ks = 0; ks < kHidden / BK; ++ks) {
#pragma unroll
    for (int i = 0; i < 4; ++i) {
      gload16(srcA[i]  + ks * BK,            &As [(w * 4 + i) * 512]);
      gload16(srcB1[i] + (size_t)ks * 8192,  &B1s[(w * 4 + i) * 512]);
      gload16(srcB3[i] + (size_t)ks * 8192,  &B3s[(w * 4 + i) * 512]);
    }
    __syncthreads();
#pragma unroll
    for (int kk = 0; kk < 2; ++kk) {
      const int cq = kk * 4 + (lane >> 4);
      bf16x8 a[4], b1v[4], b3v[4];
#pragma unroll
      for (int m = 0; m < 4; ++m) {
        int row = wr * 64 + m * 16 + (lane & 15);
        a[m] = *reinterpret_cast<const bf16x8*>(&As[row * 64 + ((cq ^ (row & 7)) << 3)]);
      }
#pragma unroll
      for (int n = 0; n < 4; ++n) {
        int row = wc * 64 + n * 16 + (lane & 15);
        b1v[n] = *reinterpret_cast<const bf16x8*>(&B1s[row * 64 + ((cq ^ (row & 7)) << 3)]);
        b3v[n] = *reinterpret_cast<const bf16x8*>(&B3s[row * 64 + ((cq ^ (row & 7)) << 3)]);
      }
#pragma unroll
      for (int m = 0; m < 4; ++m)
#pragma unroll
        for (int n = 0; n < 4; ++n) {
          accG[m][n] = __builtin_amdgcn_mfma_f32_16x16x32_bf16(a[m], b1v[n], accG[m][n], 0, 0, 0);
          accU[m][n] = __builtin_amdgcn_mfma_f32_16x16x32_bf16(a[m], b3v[n], accU[m][n], 0, 0, 0);
        }
    }
    __syncthreads();
  }

#pragma unroll
  for (int m = 0; m < 4; ++m) {
#pragma unroll
    for (int r = 0; r < 4; ++r) {
      int rloc = wr * 64 + m * 16 + ((lane >> 4) * 4) + r;
      int lrow = row0 + rloc;
      if (lrow < ne) {
        size_t base = (size_t)(sb + lrow) * kInter + (size_t)nt * BN + wc * 64 + (lane & 15);
#pragma unroll
        for (int n = 0; n < 4; ++n) {
          float g = accG[m][n][r];
          float u = accU[m][n][r];
          float hv = (g / (1.f + __expf(-g))) * u;
          hbuf[base + n * 16] = f2bf(hv);
        }
      }
    }
  }
}

// ------------- Y7 GEMM: 64x256 tiles, 3 blocks/CU forced, plain stores ------
// 4 waves; wave w owns cols w*64..+63 of the 256-col panel, all rows 0..63.
// LDS: A 8KB + B 32KB (two 128-row convert halves) + arrays = 40.8KB
//   -> exactly 3 blocks/CU (4x40.8 > 160KB). acc 4x4 = 64 AGPR; lb(256,3)
//   caps unified regs at 170 -> 3 waves/SIMD.
__global__ __launch_bounds__(256, 3) void moe_y7(
    const unsigned short* __restrict__ hbuf,
    const unsigned short* __restrict__ w2b,
    const int* __restrict__ counts, const int* __restrict__ list_idx,
    const float* __restrict__ list_w,
    float* __restrict__ ybuf)
{
  __shared__ unsigned short As[BM7 * BK];     // 8 KB
  __shared__ unsigned short Bs[2][128 * BK];  // 32 KB
  __shared__ int   toks[BM7];
  __shared__ float cofs[BM7];
  __shared__ int   rnks[BM7];

  const int tid = threadIdx.x;
  const int nt  = blockIdx.x / MAX_MT7;   // nt-major: share w2 panel in L2
  const int mt  = blockIdx.x % MAX_MT7;

  int e, lm, sb, ne;
  if (!map_tile7(counts, mt, e, lm, sb, ne)) return;
  const int row0 = lm * BM7;

  if (tid < BM7) {
    int lr = row0 + tid;
    bool v = lr < ne;
    int pk = v ? list_idx[e * kTokens + lr] : 0;
    toks[tid] = pk >> 1;
    rnks[tid] = pk & 1;
    cofs[tid] = v ? list_w[e * kTokens + lr] : 0.f;
  }
  __syncthreads();

  const int lane = tid & 63;
  const int w    = tid >> 6;   // 0..3 = col-quarter

  // A staging: 512 chunks (8KB/16B) -> 2 per thread
  const unsigned short* srcA[2];
#pragma unroll
  for (int j = 0; j < 2; ++j) {
    int l = (w * 2 + j) * 64 + lane;
    int r = l >> 3, c = (l & 7) ^ (r & 7);
    int rg = sb + row0 + r;
    if (rg > kSlotCap - 1) rg = kSlotCap - 1;
    srcA[j] = hbuf + (size_t)rg * kInter + c * 8;
  }
  // B halves = 128-row convert panels 2*nt, 2*nt+1 (lp=4, lq=6 layout);
  // each half: 1024 chunks -> 4 per thread
  const unsigned short* pB[2];
  int cOffB[4];
#pragma unroll
  for (int h = 0; h < 2; ++h)
    pB[h] = w2b + (size_t)(e * 16 + nt * 2 + h) * NTY * 8192;
#pragma unroll
  for (int i = 0; i < 4; ++i)
    cOffB[i] = ((w * 4 + i) * 64 + lane) * 8;

  f32x4 acc[4][4];
  const f32x4 zero = {0.f, 0.f, 0.f, 0.f};
#pragma unroll
  for (int m = 0; m < 4; ++m)
#pragma unroll
    for (int n = 0; n < 4; ++n) acc[m][n] = zero;

  for (int ks = 0; ks < NTY; ++ks) {
#pragma unroll
    for (int j = 0; j < 2; ++j)
      gload16(srcA[j] + ks * BK, &As[(w * 2 + j) * 512]);
#pragma unroll
    for (int i = 0; i < 4; ++i) {
      gload16(pB[0] + (size_t)ks * 8192 + cOffB[i], &Bs[0][(w * 4 + i) * 512]);
      gload16(pB[1] + (size_t)ks * 8192 + cOffB[i], &Bs[1][(w * 4 + i) * 512]);
    }
    __syncthreads();
#pragma unroll
    for (int kk = 0; kk < 2; ++kk) {
      const int cq = kk * 4 + (lane >> 4);
      bf16x8 a[4], b[4];
#pragma unroll
      for (int m = 0; m < 4; ++m) {
        int row = m * 16 + (lane & 15);
        a[m] = *reinterpret_cast<const bf16x8*>(&As[row * 64 + ((cq ^ (row & 7)) << 3)]);
      }
#pragma unroll
      for (int n = 0; n < 4; ++n) {
        int rr = w * 64 + n * 16 + (lane & 15);
        int h = rr >> 7, rl = rr & 127;
        b[n] = *reinterpret_cast<const bf16x8*>(&Bs[h][rl * 64 + ((cq ^ (rl & 7)) << 3)]);
      }
#pragma unroll
      for (int m = 0; m < 4; ++m)
#pragma unroll
        for (int n = 0; n < 4; ++n)
          acc[m][n] = __builtin_amdgcn_mfma_f32_16x16x32_bf16(a[m], b[n], acc[m][n], 0, 0, 0);
    }
    __syncthreads();
  }

  // epilogue: plain stores, each (rank,token,col) written exactly once
#pragma unroll
  for (int m = 0; m < 4; ++m) {
#pragma unroll
    for (int r = 0; r < 4; ++r) {
      int rloc = m * 16 + ((lane >> 4) * 4) + r;
      if (row0 + rloc < ne) {
        float cf = cofs[rloc];
        size_t obase = ((size_t)rnks[rloc] * kTokens + toks[rloc]) * kHidden
                     + (size_t)nt * 256 + w * 64 + (lane & 15);
#pragma unroll
        for (int n = 0; n < 4; ++n)
          ybuf[obase + n * 16] = cf * acc[m][n][r];
      }
    }
  }
}

// ---------------------------- merge: out = y0 + y1 ----------------------------
__global__ __launch_bounds__(256) void moe_merge(
    const float4* __restrict__ y0, const float4* __restrict__ y1,
    float4* __restrict__ out, int n4)
{
  int stride = gridDim.x * blockDim.x;
  for (int i = blockIdx.x * blockDim.x + threadIdx.x; i < n4; i += stride) {
    float4 a = y0[i], b = y1[i];
    float4 o; o.x = a.x + b.x; o.y = a.y + b.y; o.z = a.z + b.z; o.w = a.w + b.w;
    out[i] = o;
  }
}

// ===================== fallback (fp32 on-the-fly, atomics) ==================
__global__ __launch_bounds__(256, 2) void moe_gu_f32(
    const unsigned short* __restrict__ xb,
    const float* __restrict__ w1, const float* __restrict__ w3,
    const int* __restrict__ counts, const int* __restrict__ list_idx,
    unsigned short* __restrict__ hbuf)
{
  __shared__ unsigned short As [BM * BK];
  __shared__ unsigned short B1s[BN * BK];
  __shared__ unsigned short B3s[BN * BK];
  __shared__ int toks[BM];

  const int tid = threadIdx.x;
  const int nt  = blockIdx.x / MAX_MT;
  const int mt  = blockIdx.x % MAX_MT;

  int e, lm, sb, ne;
  if (!map_tile(counts, mt, e, lm, sb, ne)) return;
  const int row0 = lm * BM;

  if (tid < BM) {
    int lr = row0 + tid;
    toks[tid] = list_idx[e * kTokens + ((lr < ne) ? lr : 0)] >> 1;
  }
  __syncthreads();

  const unsigned short* aptr[4];
#pragma unroll
  for (int i = 0; i < 4; ++i) {
    int chunk = i * 256 + tid;
    int r = chunk >> 3, c8 = chunk & 7;
    aptr[i] = xb + (size_t)toks[r] * kHidden + c8 * 8;
  }
  const float* w1e = w1 + (size_t)e * kInter * kHidden;
  const float* w3e = w3 + (size_t)e * kInter * kHidden;

  f32x4 accG[4][4], accU[4][4];
  const f32x4 zero = {0.f, 0.f, 0.f, 0.f};
#pragma unroll
  for (int m = 0; m < 4; ++m)
#pragma unroll
    for (int n = 0; n < 4; ++n) { accG[m][n] = zero; accU[m][n] = zero; }

  const int lane = tid & 63;
  const int wr = (tid >> 6) >> 1;
  const int wc = (tid >> 6) & 1;

  for (int k0 = 0; k0 < kHidden; k0 += BK) {
#pragma unroll
    for (int i = 0; i < 4; ++i) {
      int chunk = i * 256 + tid;
      uint4 v = *reinterpret_cast<const uint4*>(aptr[i] + k0);
      *reinterpret_cast<uint4*>(&As[chunk * 8]) = v;
    }
#pragma unroll
    for (int i = 0; i < 8; ++i) {
      int c = i * 256 + tid;
      int rowB = c >> 4, c16 = c & 15;
      size_t off = ((size_t)(nt * BN + rowB)) * kHidden + k0 + c16 * 4;
      float4 v1 = *reinterpret_cast<const float4*>(w1e + off);
      float4 v3 = *reinterpret_cast<const float4*>(w3e + off);
      uint2 p1, p3;
      p1.x = (u32)f2bf(v1.x) | ((u32)f2bf(v1.y) << 16);
      p1.y = (u32)f2bf(v1.z) | ((u32)f2bf(v1.w) << 16);
      p3.x = (u32)f2bf(v3.x) | ((u32)f2bf(v3.y) << 16);
      p3.y = (u32)f2bf(v3.z) | ((u32)f2bf(v3.w) << 16);
      *reinterpret_cast<uint2*>(&B1s[rowB * BK + c16 * 4]) = p1;
      *reinterpret_cast<uint2*>(&B3s[rowB * BK + c16 * 4]) = p3;
    }
    __syncthreads();
#pragma unroll
    for (int kk = 0; kk < 2; ++kk) {
      const int klo = kk * 32 + (lane >> 4) * 8;
      bf16x8 a[4], b1v[4], b3v[4];
#pragma unroll
      for (int m = 0; m < 4; ++m)
        a[m] = *reinterpret_cast<const bf16x8*>(&As[(wr * 64 + m * 16 + (lane & 15)) * BK + klo]);
#pragma unroll
      for (int n = 0; n < 4; ++n) {
        b1v[n] = *reinterpret_cast<const bf16x8*>(&B1s[(wc * 64 + n * 16 + (lane & 15)) * BK + klo]);
        b3v[n] = *reinterpret_cast<const bf16x8*>(&B3s[(wc * 64 + n * 16 + (lane & 15)) * BK + klo]);
      }
#pragma unroll
      for (int m = 0; m < 4; ++m)
#pragma unroll
        for (int n = 0; n < 4; ++n) {
          accG[m][n] = __builtin_amdgcn_mfma_f32_16x16x32_bf16(a[m], b1v[n], accG[m][n], 0, 0, 0);
          accU[m][n] = __builtin_amdgcn_mfma_f32_16x16x32_bf16(a[m], b3v[n], accU[m][n], 0, 0, 0);
        }
    }
    __syncthreads();
  }
#pragma unroll
  for (int m = 0; m < 4; ++m) {
#pragma unroll
    for (int r = 0; r < 4; ++r) {
      int rloc = wr * 64 + m * 16 + ((lane >> 4) * 4) + r;
      int lrow = row0 + rloc;
      if (lrow < ne) {
        size_t base = (size_t)(sb + lrow) * kInter + (size_t)nt * BN + wc * 64 + (lane & 15);
#pragma unroll
        for (int n = 0; n < 4; ++n) {
          float g = accG[m][n][r];
          float u = accU[m][n][r];
          hbuf[base + n * 16] = f2bf((g / (1.f + __expf(-g))) * u);
        }
      }
    }
  }
}

__global__ __launch_bounds__(256, 2) void moe_y_f32(
    const unsigned short* __restrict__ hbuf,
    const float* __restrict__ w2,
    const int* __restrict__ counts, const int* __restrict__ list_idx,
    const float* __restrict__ list_w,
    float* __restrict__ out)
{
  __shared__ unsigned short As[BM * BK];
  __shared__ unsigned short Bs[BN * BK];
  __shared__ int   toks[BM];
  __shared__ float cofs[BM];

  const int tid = threadIdx.x;
  const int nt  = blockIdx.x / MAX_MT;
  const int mt  = blockIdx.x % MAX_MT;

  int e, lm, sb, ne;
  if (!map_tile(counts, mt, e, lm, sb, ne)) return;
  const int row0 = lm * BM;

  if (tid < BM) {
    int lr = row0 + tid;
    bool v = lr < ne;
    toks[tid] = v ? (list_idx[e * kTokens + lr] >> 1) : 0;
    cofs[tid] = v ? list_w [e * kTokens + lr] : 0.f;
  }
  __syncthreads();

  const float* w2e = w2 + (size_t)e * kHidden * kInter;
  const unsigned short* arow = hbuf + (size_t)(sb + row0) * kInter;

  f32x4 acc[4][4];
  const f32x4 zero = {0.f, 0.f, 0.f, 0.f};
#pragma unroll
  for (int m = 0; m < 4; ++m)
#pragma unroll
    for (int n = 0; n < 4; ++n) acc[m][n] = zero;

  const int lane = tid & 63;
  const int wr = (tid >> 6) >> 1;
  const int wc = (tid >> 6) & 1;

  for (int k0 = 0; k0 < kInter; k0 += BK) {
#pragma unroll
    for (int i = 0; i < 4; ++i) {
      int chunk = i * 256 + tid;
      int r = chunk >> 3, c8 = chunk & 7;
      uint4 v = *reinterpret_cast<const uint4*>(arow + (size_t)r * kInter + k0 + c8 * 8);
      *reinterpret_cast<uint4*>(&As[chunk * 8]) = v;
    }
#pragma unroll
    for (int i = 0; i < 8; ++i) {
      int c = i * 256 + tid;
      int rowB = c >> 4, c16 = c & 15;
      size_t off = ((size_t)(nt * BN + rowB)) * kInter + k0 + c16 * 4;
      float4 v2 = *reinterpret_cast<const float4*>(w2e + off);
      uint2 p2;
      p2.x = (u32)f2bf(v2.x) | ((u32)f2bf(v2.y) << 16);
      p2.y = (u32)f2bf(v2.z) | ((u32)f2bf(v2.w) << 16);
      *reinterpret_cast<uint2*>(&Bs[rowB * BK + c16 * 4]) = p2;
    }
    __syncthreads();
#pragma unroll
    for (int kk = 0; kk < 2; ++kk) {
      const int klo = kk * 32 + (lane >> 4) * 8;
      bf16x8 a[4], b[4];
#pragma unroll
      for (int m = 0; m < 4; ++m)
        a[m] = *reinterpret_cast<const bf16x8*>(&As[(wr * 64 + m * 16 + (lane & 15)) * BK + klo]);
#pragma unroll
      for (int n = 0; n < 4; ++n)
        b[n] = *reinterpret_cast<const bf16x8*>(&Bs[(wc * 64 + n * 16 + (lane & 15)) * BK + klo]);
#pragma unroll
      for (int m = 0; m < 4; ++m)
#pragma unroll
        for (int n = 0; n < 4; ++n)
          acc[m][n] = __builtin_amdgcn_mfma_f32_16x16x32_bf16(a[m], b[n], acc[m][n], 0, 0, 0);
    }
    __syncthreads();
  }
#pragma unroll
  for (int m = 0; m < 4; ++m) {
#pragma unroll
    for (int r = 0; r < 4; ++r) {
      int rloc = wr * 64 + m * 16 + ((lane >> 4) * 4) + r;
      if (row0 + rloc < ne) {
        float cf = cofs[rloc];
        size_t obase = (size_t)toks[rloc] * kHidden + (size_t)nt * BN + wc * 64 + (lane & 15);
#pragma unroll
        for (int n = 0; n < 4; ++n)
          atomicAdd(&out[obase + n * 16], cf * acc[m][n][r]);
      }
    }
  }
}

// ---------------------------- host ----------------------------
extern "C" void kernel_launch(void* const* d_in, const int* in_sizes, int n_in,
                              void* d_out, int out_size, void* d_ws, size_t ws_size,
                              hipStream_t stream)
{
  const float* x      = (const float*)d_in[0];
  const float* gate_w = (const float*)d_in[1];
  const float* w1     = (const float*)d_in[2];
  const float* w2     = (const float*)d_in[3];
  const float* w3     = (const float*)d_in[4];
  float* out = (float*)d_out;

  char* ws = (char*)d_ws;
  const size_t MiB = 1ull << 20;
  int*   counts   = (int*)(ws);
  int*   list_idx = (int*)(ws + 1024);
  float* list_w   = (float*)(ws + 1024 + kExperts * kTokens * 4);

  hipMemsetAsync(counts, 0, 1024, stream);

  if (ws_size >= 418 * MiB) {
    unsigned short* xb   = (unsigned short*)(ws + 1 * MiB);
    unsigned short* w1b  = (unsigned short*)(ws + 33 * MiB);
    unsigned short* w3b  = (unsigned short*)(ws + 161 * MiB);
    unsigned short* hbuf = (unsigned short*)(ws + 289 * MiB);
    unsigned short* w2b  = w1b;                       // reuse after GU
    float*          ybuf = (float*)(ws + 161 * MiB);  // reuse w3b after GU

    const long nch = (long)kExperts * 32 * 32 * 1024;  // same for all 3 weights
    convert_w<<<4096, 256, 0, stream>>>(w1, w1b, 5, 5, kHidden, nch);
    convert_w<<<4096, 256, 0, stream>>>(w3, w3b, 5, 5, kHidden, nch);
    moe_router<<<kTokens / 4, 256, 0, stream>>>(x, gate_w, xb, counts, list_idx, list_w);
    moe_gu<<<(kInter / BN) * MAX_MT, 256, 0, stream>>>(xb, w1b, w3b, counts, list_idx, hbuf);
    convert_w<<<4096, 256, 0, stream>>>(w2, w2b, 4, 6, kInter, nch);
    moe_y7<<<(kHidden / 256) * MAX_MT7, 256, 0, stream>>>(hbuf, w2b, counts, list_idx, list_w, ybuf);
    moe_merge<<<2048, 256, 0, stream>>>(
        (const float4*)ybuf, (const float4*)(ybuf + (size_t)kTokens * kHidden),
        (float4*)out, kTokens * kHidden / 4);
  } else {
    unsigned short* xb   = (unsigned short*)(ws + 1 * MiB);
    unsigned short* hbuf = (unsigned short*)(ws + 36 * MiB);
    hipMemsetAsync(out, 0, (size_t)kTokens * kHidden * sizeof(float), stream);
    moe_router<<<kTokens / 4, 256, 0, stream>>>(x, gate_w, xb, counts, list_idx, list_w);
    moe_gu_f32<<<(kInter / BN) * MAX_MT, 256, 0, stream>>>(xb, w1, w3, counts, list_idx, hbuf);
    moe_y_f32 <<<(kHidden / BN) * MAX_MT, 256, 0, stream>>>(hbuf, w2, counts, list_idx, list_w, out);
  }
}

// Round 12
// 1409.947 us; speedup vs baseline: 1.0664x; 1.0664x over previous
//
#include <hip/hip_runtime.h>
#include <stdint.h>
#include <stddef.h>

// ---------------------------------------------------------------------------
// Sparse top-2 MoE, bf16 MFMA, fp32 accumulate.
//   prep:    ONE kernel = router (2048 blks) + w1->bf16 (4096) + w3->bf16
//            (4096); independent work, previously serialized launches.
//   GU:      h = silu(x@w1^T) * (x@w3^T)   [byte-exact r2 structure, 625us]
//   Y8:      Y5 (128x256, 512thr, 8 panels) + SPLIT-K=2: 2176 blocks ->
//            5 rounds @ half-tile time (85% packing vs Y5's 71%).
//            bf16 partials -> ybuf16[rank*2+ks][tok][col] (128 MiB).
//   merge4:  out = sum of 4 bf16 partial buffers (fp32 accumulate).
// nt-major dispatch: co-resident blocks share the weight panel (L2-hot).
// ws layout (MiB): [0,1) lists | [1,33) xb | [33,161) w1b (later w2b)
//                  [161,289) w3b (later ybuf16[4]) | [289,418) hbuf
// ---------------------------------------------------------------------------

constexpr int kTokens  = 8192;
constexpr int kHidden  = 2048;
constexpr int kInter   = 4096;
constexpr int kExperts = 8;

constexpr int BM = 128, BN = 128, BK = 64;
constexpr int MAX_MT = (2 * kTokens) / BM + kExperts;   // 136
constexpr int NTY = kInter / BK;                        // 64 K-tiles (Y)
constexpr int kSlotCap = 16512;                         // hbuf rows incl. slack

typedef short bf16x8 __attribute__((ext_vector_type(8)));
typedef float f32x4  __attribute__((ext_vector_type(4)));
typedef unsigned int u32;

__device__ __forceinline__ unsigned short f2bf(float f) {
  union { float f; unsigned u; } v; v.f = f;
  unsigned r = v.u + 0x7FFFu + ((v.u >> 16) & 1u);  // RTNE
  return (unsigned short)(r >> 16);
}

__device__ __forceinline__ void gload16(const void* g, void* l) {
  __builtin_amdgcn_global_load_lds(
      (const __attribute__((address_space(1))) u32*)g,
      (__attribute__((address_space(3))) u32*)l, 16, 0, 0);
}

// ---------------------------- convert body (proven r2 layout) ---------------
__device__ __forceinline__ void convert_body(
    const float* __restrict__ src, unsigned short* __restrict__ dst,
    int lp, int lq, int K, long nchunks, int bid, int nblocks)
{
  long stride = (long)nblocks * 256;
  for (long g = bid * 256L + threadIdx.x; g < nchunks; g += stride) {
    int  l   = (int)(g & 1023);
    long blk = g >> 10;
    int  q   = (int)(blk & ((1 << lq) - 1));
    long ep  = blk >> lq;
    int  p   = (int)(ep & ((1 << lp) - 1));
    int  e   = (int)(ep >> lp);
    int r = l >> 3, cs = l & 7, c = cs ^ (r & 7);
    size_t soff = (((size_t)(e << lp) + p) * 128 + r) * (size_t)K + (size_t)q * 64 + c * 8;
    float4 v0 = *reinterpret_cast<const float4*>(src + soff);
    float4 v1 = *reinterpret_cast<const float4*>(src + soff + 4);
    uint4 o;
    o.x = (u32)f2bf(v0.x) | ((u32)f2bf(v0.y) << 16);
    o.y = (u32)f2bf(v0.z) | ((u32)f2bf(v0.w) << 16);
    o.z = (u32)f2bf(v1.x) | ((u32)f2bf(v1.y) << 16);
    o.w = (u32)f2bf(v1.z) | ((u32)f2bf(v1.w) << 16);
    *reinterpret_cast<uint4*>(dst + g * 8) = o;
  }
}

__global__ __launch_bounds__(256) void convert_w(
    const float* __restrict__ src, unsigned short* __restrict__ dst,
    int lp, int lq, int K, long nchunks)
{
  convert_body(src, dst, lp, lq, K, nchunks, blockIdx.x, gridDim.x);
}

// ------------- router body (idx packed t*2+rank) -------------
__device__ __forceinline__ void router_body(
    const float* __restrict__ x, const float* __restrict__ gate_w,
    unsigned short* __restrict__ xb, int* __restrict__ counts,
    int* __restrict__ list_idx, float* __restrict__ list_w, int bid)
{
  const int lane = threadIdx.x & 63;
  const int wave = threadIdx.x >> 6;
  const int t = bid * 4 + wave;

  float acc[kExperts];
#pragma unroll
  for (int e = 0; e < kExperts; ++e) acc[e] = 0.f;

  const float4* xrow = reinterpret_cast<const float4*>(x + (size_t)t * kHidden);
#pragma unroll
  for (int j = 0; j < 8; ++j) {
    float4 xv = xrow[j * 64 + lane];
    uint2 pk;
    pk.x = (u32)f2bf(xv.x) | ((u32)f2bf(xv.y) << 16);
    pk.y = (u32)f2bf(xv.z) | ((u32)f2bf(xv.w) << 16);
    *reinterpret_cast<uint2*>(xb + (size_t)t * kHidden + j * 256 + lane * 4) = pk;
#pragma unroll
    for (int e = 0; e < kExperts; ++e) {
      float4 gv = reinterpret_cast<const float4*>(gate_w + (size_t)e * kHidden)[j * 64 + lane];
      acc[e] += xv.x * gv.x + xv.y * gv.y + xv.z * gv.z + xv.w * gv.w;
    }
  }
#pragma unroll
  for (int e = 0; e < kExperts; ++e) {
#pragma unroll
    for (int m = 32; m >= 1; m >>= 1) acc[e] += __shfl_xor(acc[e], m);
  }
  if (lane == 0) {
    float mx = acc[0];
#pragma unroll
    for (int e = 1; e < kExperts; ++e) mx = fmaxf(mx, acc[e]);
    float p[kExperts]; float s = 0.f;
#pragma unroll
    for (int e = 0; e < kExperts; ++e) { p[e] = __expf(acc[e] - mx); s += p[e]; }
    float inv = 1.f / s;
    int i1 = 0; float v1 = p[0];
#pragma unroll
    for (int e = 1; e < kExperts; ++e) if (p[e] > v1) { v1 = p[e]; i1 = e; }
    int i2 = (i1 == 0) ? 1 : 0; float v2 = p[i2];
#pragma unroll
    for (int e = 0; e < kExperts; ++e) {
      if (e == i1 || e == i2) continue;
      if (p[e] > v2) { v2 = p[e]; i2 = e; }
    }
    int s1 = atomicAdd(&counts[i1], 1);
    list_idx[i1 * kTokens + s1] = t * 2 + 0;
    list_w [i1 * kTokens + s1] = v1 * inv;
    int s2 = atomicAdd(&counts[i2], 1);
    list_idx[i2 * kTokens + s2] = t * 2 + 1;
    list_w [i2 * kTokens + s2] = v2 * inv;
  }
}

// ------------- prep: router + w1 convert + w3 convert, one launch -----------
__global__ __launch_bounds__(256) void moe_prep(
    const float* __restrict__ x, const float* __restrict__ gate_w,
    unsigned short* __restrict__ xb, int* __restrict__ counts,
    int* __restrict__ list_idx, float* __restrict__ list_w,
    const float* __restrict__ w1, unsigned short* __restrict__ w1b,
    const float* __restrict__ w3, unsigned short* __restrict__ w3b,
    long nchunks)
{
  const int bid = blockIdx.x;
  if (bid < 2048) {
    router_body(x, gate_w, xb, counts, list_idx, list_w, bid);
  } else if (bid < 2048 + 4096) {
    convert_body(w1, w1b, 5, 5, kHidden, nchunks, bid - 2048, 4096);
  } else {
    convert_body(w3, w3b, 5, 5, kHidden, nchunks, bid - 6144, 4096);
  }
}

// standalone router (fallback path)
__global__ __launch_bounds__(256) void moe_router(
    const float* __restrict__ x, const float* __restrict__ gate_w,
    unsigned short* __restrict__ xb, int* __restrict__ counts,
    int* __restrict__ list_idx, float* __restrict__ list_w)
{
  router_body(x, gate_w, xb, counts, list_idx, list_w, blockIdx.x);
}

// ------------------- tile mapping helper -------------------
__device__ __forceinline__ bool map_tile(const int* __restrict__ counts, int mt,
                                         int& e, int& lm, int& sb, int& ne)
{
  int tb = 0; sb = 0;
  for (e = 0; e < kExperts; ++e) {
    ne = counts[e];
    int tiles = (ne + BM - 1) / BM;
    if (mt < tb + tiles) { lm = mt - tb; return true; }
    tb += tiles; sb += ne;
  }
  return false;
}

// ---------------------------- GU GEMM (byte-exact r2, 625us) ----------------
__global__ __launch_bounds__(256, 2) void moe_gu(
    const unsigned short* __restrict__ xb,
    const unsigned short* __restrict__ w1b, const unsigned short* __restrict__ w3b,
    const int* __restrict__ counts, const int* __restrict__ list_idx,
    unsigned short* __restrict__ hbuf)
{
  __shared__ unsigned short As [BM * BK];
  __shared__ unsigned short B1s[BN * BK];
  __shared__ unsigned short B3s[BN * BK];
  __shared__ int toks[BM];

  const int tid = threadIdx.x;
  const int nt  = blockIdx.x / MAX_MT;
  const int mt  = blockIdx.x % MAX_MT;

  int e, lm, sb, ne;
  if (!map_tile(counts, mt, e, lm, sb, ne)) return;
  const int row0 = lm * BM;

  if (tid < BM) {
    int lr = row0 + tid;
    toks[tid] = list_idx[e * kTokens + ((lr < ne) ? lr : 0)] >> 1;
  }
  __syncthreads();

  const int lane = tid & 63;
  const int w = tid >> 6;
  const int wr = w >> 1, wc = w & 1;

  const unsigned short* srcA[4];
  const unsigned short* srcB1[4];
  const unsigned short* srcB3[4];
  const size_t bbase = ((size_t)(e * (kInter / BN) + nt) * (kHidden / BK)) * 1024;
#pragma unroll
  for (int i = 0; i < 4; ++i) {
    int l = (w * 4 + i) * 64 + lane;
    int r = l >> 3, cs = l & 7, c = cs ^ (r & 7);
    srcA[i]  = xb  + (size_t)toks[r] * kHidden + c * 8;
    srcB1[i] = w1b + (bbase + l) * 8;
    srcB3[i] = w3b + (bbase + l) * 8;
  }

  f32x4 accG[4][4], accU[4][4];
  const f32x4 zero = {0.f, 0.f, 0.f, 0.f};
#pragma unroll
  for (int m = 0; m < 4; ++m)
#pragma unroll
    for (int n = 0; n < 4; ++n) { accG[m][n] = zero; accU[m][n] = zero; }

  for (int ks = 0; ks < kHidden / BK; ++ks) {
#pragma unroll
    for (int i = 0; i < 4; ++i) {
      gload16(srcA[i]  + ks * BK,            &As [(w * 4 + i) * 512]);
      gload16(srcB1[i] + (size_t)ks * 8192,  &B1s[(w * 4 + i) * 512]);
      gload16(srcB3[i] + (size_t)ks * 8192,  &B3s[(w * 4 + i) * 512]);
    }
    __syncthreads();
#pragma unroll
    for (int kk = 0; kk < 2; ++kk) {
      const int cq = kk * 4 + (lane >> 4);
      bf16x8 a[4], b1v[4], b3v[4];
#pragma unroll
      for (int m = 0; m < 4; ++m) {
        int row = wr * 64 + m * 16 + (lane & 15);
        a[m] = *reinterpret_cast<const bf16x8*>(&As[row * 64 + ((cq ^ (row & 7)) << 3)]);
      }
#pragma unroll
      for (int n = 0; n < 4; ++n) {
        int row = wc * 64 + n * 16 + (lane & 15);
        b1v[n] = *reinterpret_cast<const bf16x8*>(&B1s[row * 64 + ((cq ^ (row & 7)) << 3)]);
        b3v[n] = *reinterpret_cast<const bf16x8*>(&B3s[row * 64 + ((cq ^ (row & 7)) << 3)]);
      }
#pragma unroll
      for (int m = 0; m < 4; ++m)
#pragma unroll
        for (int n = 0; n < 4; ++n) {
          accG[m][n] = __builtin_amdgcn_mfma_f32_16x16x32_bf16(a[m], b1v[n], accG[m][n], 0, 0, 0);
          accU[m][n] = __builtin_amdgcn_mfma_f32_16x16x32_bf16(a[m], b3v[n], accU[m][n], 0, 0, 0);
        }
    }
    __syncthreads();
  }

#pragma unroll
  for (int m = 0; m < 4; ++m) {
#pragma unroll
    for (int r = 0; r < 4; ++r) {
      int rloc = wr * 64 + m * 16 + ((lane >> 4) * 4) + r;
      int lrow = row0 + rloc;
      if (lrow < ne) {
        size_t base = (size_t)(sb + lrow) * kInter + (size_t)nt * BN + wc * 64 + (lane & 15);
#pragma unroll
        for (int n = 0; n < 4; ++n) {
          float g = accG[m][n][r];
          float u = accU[m][n][r];
          float hv = (g / (1.f + __expf(-g))) * u;
          hbuf[base + n * 16] = f2bf(hv);
        }
      }
    }
  }
}

// ------------- Y8: Y5 structure + split-K=2, bf16 partial stores -------------
// 16 groups (ks 0..1 x nt 0..7) x 136 mt = 2176 blocks of 512thr.
// Each block: K-half [ks*32, ks*32+32) tiles; wave (wr,wc) = 64x64 output.
// Partial stored bf16 to ybuf16[(rank*2+ks)][tok][col].
__global__ __launch_bounds__(512, 2) void moe_y8(
    const unsigned short* __restrict__ hbuf,
    const unsigned short* __restrict__ w2b,
    const int* __restrict__ counts, const int* __restrict__ list_idx,
    const float* __restrict__ list_w,
    unsigned short* __restrict__ ybuf16)
{
  __shared__ unsigned short As[8192];
  __shared__ unsigned short Bs[2][8192];
  __shared__ int   toks[BM];
  __shared__ float cofs[BM];
  __shared__ int   rnks[BM];

  const int tid = threadIdx.x;
  const int grp = blockIdx.x / MAX_MT;   // 0..15
  const int mt  = blockIdx.x % MAX_MT;
  const int ks  = grp >> 3;              // 0..1 K-half
  const int nt  = grp & 7;               // 0..7 col panel (256)

  int e, lm, sb, ne;
  if (!map_tile(counts, mt, e, lm, sb, ne)) return;
  const int row0 = lm * BM;

  if (tid < BM) {
    int lr = row0 + tid;
    bool v = lr < ne;
    int pk = v ? list_idx[e * kTokens + lr] : 0;
    toks[tid] = pk >> 1;
    rnks[tid] = pk & 1;
    cofs[tid] = v ? list_w[e * kTokens + lr] : 0.f;
  }
  __syncthreads();

  const int lane = tid & 63;
  const int w    = tid >> 6;
  const int wr   = w >> 2;   // 0..1
  const int wc   = w & 3;    // 0..3

  const unsigned short* srcA[2];
  int cOff[2];
#pragma unroll
  for (int j = 0; j < 2; ++j) {
    int l = (w * 2 + j) * 64 + lane;
    int r = l >> 3, c = (l & 7) ^ (r & 7);
    int rg = sb + row0 + r;
    if (rg > kSlotCap - 1) rg = kSlotCap - 1;
    srcA[j] = hbuf + (size_t)rg * kInter + c * 8;
    cOff[j] = l * 8;
  }
  // B halves = 128-row convert panels 2*nt, 2*nt+1 (lp=4, lq=6 layout)
  const unsigned short* pB[2];
#pragma unroll
  for (int h = 0; h < 2; ++h)
    pB[h] = w2b + (size_t)(e * 16 + nt * 2 + h) * NTY * 8192;

  f32x4 acc[4][4];
  const f32x4 zero = {0.f, 0.f, 0.f, 0.f};
#pragma unroll
  for (int m = 0; m < 4; ++m)
#pragma unroll
    for (int n = 0; n < 4; ++n) acc[m][n] = zero;

  const int kt0 = ks * (NTY / 2);
  for (int kt = kt0; kt < kt0 + NTY / 2; ++kt) {
#pragma unroll
    for (int j = 0; j < 2; ++j) {
      gload16(srcA[j] + kt * BK, &As[(w * 2 + j) * 512]);
      gload16(pB[0] + (size_t)kt * 8192 + cOff[j], &Bs[0][(w * 2 + j) * 512]);
      gload16(pB[1] + (size_t)kt * 8192 + cOff[j], &Bs[1][(w * 2 + j) * 512]);
    }
    __syncthreads();
#pragma unroll
    for (int kk = 0; kk < 2; ++kk) {
      const int cq = kk * 4 + (lane >> 4);
      bf16x8 a[4], b[4];
#pragma unroll
      for (int m = 0; m < 4; ++m) {
        int row = wr * 64 + m * 16 + (lane & 15);
        a[m] = *reinterpret_cast<const bf16x8*>(&As[row * 64 + ((cq ^ (row & 7)) << 3)]);
      }
#pragma unroll
      for (int n = 0; n < 4; ++n) {
        int rr = wc * 64 + n * 16 + (lane & 15);
        int h = rr >> 7, rl = rr & 127;
        b[n] = *reinterpret_cast<const bf16x8*>(&Bs[h][rl * 64 + ((cq ^ (rl & 7)) << 3)]);
      }
#pragma unroll
      for (int m = 0; m < 4; ++m)
#pragma unroll
        for (int n = 0; n < 4; ++n)
          acc[m][n] = __builtin_amdgcn_mfma_f32_16x16x32_bf16(a[m], b[n], acc[m][n], 0, 0, 0);
    }
    __syncthreads();
  }

  // epilogue: bf16 partial, each (rank,ks,token,col) written exactly once
#pragma unroll
  for (int m = 0; m < 4; ++m) {
#pragma unroll
    for (int r = 0; r < 4; ++r) {
      int rloc = wr * 64 + m * 16 + ((lane >> 4) * 4) + r;
      if (row0 + rloc < ne) {
        float cf = cofs[rloc];
        size_t obase = ((size_t)(rnks[rloc] * 2 + ks) * kTokens + toks[rloc]) * kHidden
                     + (size_t)nt * 256 + wc * 64 + (lane & 15);
#pragma unroll
        for (int n = 0; n < 4; ++n)
          ybuf16[obase + n * 16] = f2bf(cf * acc[m][n][r]);
      }
    }
  }
}

// ---------------------------- merge4: out = sum of 4 bf16 partials ----------
__global__ __launch_bounds__(256) void moe_merge4(
    const unsigned short* __restrict__ yb, float* __restrict__ out, long n8)
{
  const size_t bs = (size_t)kTokens * kHidden;  // shorts per buffer
  long stride = (long)gridDim.x * blockDim.x;
  for (long i = blockIdx.x * (long)blockDim.x + threadIdx.x; i < n8; i += stride) {
    float s[8];
#pragma unroll
    for (int k = 0; k < 8; ++k) s[k] = 0.f;
#pragma unroll
    for (int b = 0; b < 4; ++b) {
      uint4 v = *reinterpret_cast<const uint4*>(yb + b * bs + (size_t)i * 8);
      const unsigned short* h = reinterpret_cast<const unsigned short*>(&v);
#pragma unroll
      for (int k = 0; k < 8; ++k) {
        union { unsigned u; float f; } cv; cv.u = (unsigned)h[k] << 16;
        s[k] += cv.f;
      }
    }
    float4 o0 = {s[0], s[1], s[2], s[3]};
    float4 o1 = {s[4], s[5], s[6], s[7]};
    *reinterpret_cast<float4*>(out + (size_t)i * 8)     = o0;
    *reinterpret_cast<float4*>(out + (size_t)i * 8 + 4) = o1;
  }
}

// ===================== fallback (fp32 on-the-fly, atomics) ==================
__global__ __launch_bounds__(256, 2) void moe_gu_f32(
    const unsigned short* __restrict__ xb,
    const float* __restrict__ w1, const float* __restrict__ w3,
    const int* __restrict__ counts, const int* __restrict__ list_idx,
    unsigned short* __restrict__ hbuf)
{
  __shared__ unsigned short As [BM * BK];
  __shared__ unsigned short B1s[BN * BK];
  __shared__ unsigned short B3s[BN * BK];
  __shared__ int toks[BM];

  const int tid = threadIdx.x;
  const int nt  = blockIdx.x / MAX_MT;
  const int mt  = blockIdx.x % MAX_MT;

  int e, lm, sb, ne;
  if (!map_tile(counts, mt, e, lm, sb, ne)) return;
  const int row0 = lm * BM;

  if (tid < BM) {
    int lr = row0 + tid;
    toks[tid] = list_idx[e * kTokens + ((lr < ne) ? lr : 0)] >> 1;
  }
  __syncthreads();

  const unsigned short* aptr[4];
#pragma unroll
  for (int i = 0; i < 4; ++i) {
    int chunk = i * 256 + tid;
    int r = chunk >> 3, c8 = chunk & 7;
    aptr[i] = xb + (size_t)toks[r] * kHidden + c8 * 8;
  }
  const float* w1e = w1 + (size_t)e * kInter * kHidden;
  const float* w3e = w3 + (size_t)e * kInter * kHidden;

  f32x4 accG[4][4], accU[4][4];
  const f32x4 zero = {0.f, 0.f, 0.f, 0.f};
#pragma unroll
  for (int m = 0; m < 4; ++m)
#pragma unroll
    for (int n = 0; n < 4; ++n) { accG[m][n] = zero; accU[m][n] = zero; }

  const int lane = tid & 63;
  const int wr = (tid >> 6) >> 1;
  const int wc = (tid >> 6) & 1;

  for (int k0 = 0; k0 < kHidden; k0 += BK) {
#pragma unroll
    for (int i = 0; i < 4; ++i) {
      int chunk = i * 256 + tid;
      uint4 v = *reinterpret_cast<const uint4*>(aptr[i] + k0);
      *reinterpret_cast<uint4*>(&As[chunk * 8]) = v;
    }
#pragma unroll
    for (int i = 0; i < 8; ++i) {
      int c = i * 256 + tid;
      int rowB = c >> 4, c16 = c & 15;
      size_t off = ((size_t)(nt * BN + rowB)) * kHidden + k0 + c16 * 4;
      float4 v1 = *reinterpret_cast<const float4*>(w1e + off);
      float4 v3 = *reinterpret_cast<const float4*>(w3e + off);
      uint2 p1, p3;
      p1.x = (u32)f2bf(v1.x) | ((u32)f2bf(v1.y) << 16);
      p1.y = (u32)f2bf(v1.z) | ((u32)f2bf(v1.w) << 16);
      p3.x = (u32)f2bf(v3.x) | ((u32)f2bf(v3.y) << 16);
      p3.y = (u32)f2bf(v3.z) | ((u32)f2bf(v3.w) << 16);
      *reinterpret_cast<uint2*>(&B1s[rowB * BK + c16 * 4]) = p1;
      *reinterpret_cast<uint2*>(&B3s[rowB * BK + c16 * 4]) = p3;
    }
    __syncthreads();
#pragma unroll
    for (int kk = 0; kk < 2; ++kk) {
      const int klo = kk * 32 + (lane >> 4) * 8;
      bf16x8 a[4], b1v[4], b3v[4];
#pragma unroll
      for (int m = 0; m < 4; ++m)
        a[m] = *reinterpret_cast<const bf16x8*>(&As[(wr * 64 + m * 16 + (lane & 15)) * BK + klo]);
#pragma unroll
      for (int n = 0; n < 4; ++n) {
        b1v[n] = *reinterpret_cast<const bf16x8*>(&B1s[(wc * 64 + n * 16 + (lane & 15)) * BK + klo]);
        b3v[n] = *reinterpret_cast<const bf16x8*>(&B3s[(wc * 64 + n * 16 + (lane & 15)) * BK + klo]);
      }
#pragma unroll
      for (int m = 0; m < 4; ++m)
#pragma unroll
        for (int n = 0; n < 4; ++n) {
          accG[m][n] = __builtin_amdgcn_mfma_f32_16x16x32_bf16(a[m], b1v[n], accG[m][n], 0, 0, 0);
          accU[m][n] = __builtin_amdgcn_mfma_f32_16x16x32_bf16(a[m], b3v[n], accU[m][n], 0, 0, 0);
        }
    }
    __syncthreads();
  }
#pragma unroll
  for (int m = 0; m < 4; ++m) {
#pragma unroll
    for (int r = 0; r < 4; ++r) {
      int rloc = wr * 64 + m * 16 + ((lane >> 4) * 4) + r;
      int lrow = row0 + rloc;
      if (lrow < ne) {
        size_t base = (size_t)(sb + lrow) * kInter + (size_t)nt * BN + wc * 64 + (lane & 15);
#pragma unroll
        for (int n = 0; n < 4; ++n) {
          float g = accG[m][n][r];
          float u = accU[m][n][r];
          hbuf[base + n * 16] = f2bf((g / (1.f + __expf(-g))) * u);
        }
      }
    }
  }
}

__global__ __launch_bounds__(256, 2) void moe_y_f32(
    const unsigned short* __restrict__ hbuf,
    const float* __restrict__ w2,
    const int* __restrict__ counts, const int* __restrict__ list_idx,
    const float* __restrict__ list_w,
    float* __restrict__ out)
{
  __shared__ unsigned short As[BM * BK];
  __shared__ unsigned short Bs[BN * BK];
  __shared__ int   toks[BM];
  __shared__ float cofs[BM];

  const int tid = threadIdx.x;
  const int nt  = blockIdx.x / MAX_MT;
  const int mt  = blockIdx.x % MAX_MT;

  int e, lm, sb, ne;
  if (!map_tile(counts, mt, e, lm, sb, ne)) return;
  const int row0 = lm * BM;

  if (tid < BM) {
    int lr = row0 + tid;
    bool v = lr < ne;
    toks[tid] = v ? (list_idx[e * kTokens + lr] >> 1) : 0;
    cofs[tid] = v ? list_w [e * kTokens + lr] : 0.f;
  }
  __syncthreads();

  const float* w2e = w2 + (size_t)e * kHidden * kInter;
  const unsigned short* arow = hbuf + (size_t)(sb + row0) * kInter;

  f32x4 acc[4][4];
  const f32x4 zero = {0.f, 0.f, 0.f, 0.f};
#pragma unroll
  for (int m = 0; m < 4; ++m)
#pragma unroll
    for (int n = 0; n < 4; ++n) acc[m][n] = zero;

  const int lane = tid & 63;
  const int wr = (tid >> 6) >> 1;
  const int wc = (tid >> 6) & 1;

  for (int k0 = 0; k0 < kInter; k0 += BK) {
#pragma unroll
    for (int i = 0; i < 4; ++i) {
      int chunk = i * 256 + tid;
      int r = chunk >> 3, c8 = chunk & 7;
      uint4 v = *reinterpret_cast<const uint4*>(arow + (size_t)r * kInter + k0 + c8 * 8);
      *reinterpret_cast<uint4*>(&As[chunk * 8]) = v;
    }
#pragma unroll
    for (int i = 0; i < 8; ++i) {
      int c = i * 256 + tid;
      int rowB = c >> 4, c16 = c & 15;
      size_t off = ((size_t)(nt * BN + rowB)) * kInter + k0 + c16 * 4;
      float4 v2 = *reinterpret_cast<const float4*>(w2e + off);
      uint2 p2;
      p2.x = (u32)f2bf(v2.x) | ((u32)f2bf(v2.y) << 16);
      p2.y = (u32)f2bf(v2.z) | ((u32)f2bf(v2.w) << 16);
      *reinterpret_cast<uint2*>(&Bs[rowB * BK + c16 * 4]) = p2;
    }
    __syncthreads();
#pragma unroll
    for (int kk = 0; kk < 2; ++kk) {
      const int klo = kk * 32 + (lane >> 4) * 8;
      bf16x8 a[4], b[4];
#pragma unroll
      for (int m = 0; m < 4; ++m)
        a[m] = *reinterpret_cast<const bf16x8*>(&As[(wr * 64 + m * 16 + (lane & 15)) * BK + klo]);
#pragma unroll
      for (int n = 0; n < 4; ++n)
        b[n] = *reinterpret_cast<const bf16x8*>(&Bs[(wc * 64 + n * 16 + (lane & 15)) * BK + klo]);
#pragma unroll
      for (int m = 0; m < 4; ++m)
#pragma unroll
        for (int n = 0; n < 4; ++n)
          acc[m][n] = __builtin_amdgcn_mfma_f32_16x16x32_bf16(a[m], b[n], acc[m][n], 0, 0, 0);
    }
    __syncthreads();
  }
#pragma unroll
  for (int m = 0; m < 4; ++m) {
#pragma unroll
    for (int r = 0; r < 4; ++r) {
      int rloc = wr * 64 + m * 16 + ((lane >> 4) * 4) + r;
      if (row0 + rloc < ne) {
        float cf = cofs[rloc];
        size_t obase = (size_t)toks[rloc] * kHidden + (size_t)nt * BN + wc * 64 + (lane & 15);
#pragma unroll
        for (int n = 0; n < 4; ++n)
          atomicAdd(&out[obase + n * 16], cf * acc[m][n][r]);
      }
    }
  }
}

// ---------------------------- host ----------------------------
extern "C" void kernel_launch(void* const* d_in, const int* in_sizes, int n_in,
                              void* d_out, int out_size, void* d_ws, size_t ws_size,
                              hipStream_t stream)
{
  const float* x      = (const float*)d_in[0];
  const float* gate_w = (const float*)d_in[1];
  const float* w1     = (const float*)d_in[2];
  const float* w2     = (const float*)d_in[3];
  const float* w3     = (const float*)d_in[4];
  float* out = (float*)d_out;

  char* ws = (char*)d_ws;
  const size_t MiB = 1ull << 20;
  int*   counts   = (int*)(ws);
  int*   list_idx = (int*)(ws + 1024);
  float* list_w   = (float*)(ws + 1024 + kExperts * kTokens * 4);

  hipMemsetAsync(counts, 0, 1024, stream);

  if (ws_size >= 418 * MiB) {
    unsigned short* xb     = (unsigned short*)(ws + 1 * MiB);
    unsigned short* w1b    = (unsigned short*)(ws + 33 * MiB);
    unsigned short* w3b    = (unsigned short*)(ws + 161 * MiB);
    unsigned short* hbuf   = (unsigned short*)(ws + 289 * MiB);
    unsigned short* w2b    = w1b;                              // reuse after GU
    unsigned short* ybuf16 = (unsigned short*)(ws + 161 * MiB); // reuse w3b after GU

    const long nch = (long)kExperts * 32 * 32 * 1024;  // same for all 3 weights
    moe_prep<<<10240, 256, 0, stream>>>(x, gate_w, xb, counts, list_idx, list_w,
                                        w1, w1b, w3, w3b, nch);
    moe_gu<<<(kInter / BN) * MAX_MT, 256, 0, stream>>>(xb, w1b, w3b, counts, list_idx, hbuf);
    convert_w<<<4096, 256, 0, stream>>>(w2, w2b, 4, 6, kInter, nch);
    moe_y8<<<16 * MAX_MT, 512, 0, stream>>>(hbuf, w2b, counts, list_idx, list_w, ybuf16);
    moe_merge4<<<2048, 256, 0, stream>>>(ybuf16, out, (long)kTokens * kHidden / 8);
  } else {
    unsigned short* xb   = (unsigned short*)(ws + 1 * MiB);
    unsigned short* hbuf = (unsigned short*)(ws + 36 * MiB);
    hipMemsetAsync(out, 0, (size_t)kTokens * kHidden * sizeof(float), stream);
    moe_router<<<kTokens / 4, 256, 0, stream>>>(x, gate_w, xb, counts, list_idx, list_w);
    moe_gu_f32<<<(kInter / BN) * MAX_MT, 256, 0, stream>>>(xb, w1, w3, counts, list_idx, hbuf);
    moe_y_f32 <<<(kHidden / BN) * MAX_MT, 256, 0, stream>>>(hbuf, w2, counts, list_idx, list_w, out);
  }
}

// Round 13
// 1393.018 us; speedup vs baseline: 1.0794x; 1.0122x over previous
//
#include <hip/hip_runtime.h>
#include <stdint.h>
#include <stddef.h>

// ---------------------------------------------------------------------------
// Sparse top-2 MoE, bf16 MFMA, fp32 accumulate.
//   prep:    ONE kernel = router (2048 blks) + w1->bf16 (4096) + w3->bf16.
//   GU:      h = silu(x@w1^T) * (x@w3^T)  [r2 structure, 625us] — if ws
//            allows, FUSED with w2->bf16 convert (4096 extra blocks) to hide
//            the convert under GU's idle HBM bandwidth (GU is 35% HBM).
//   Y8:      128x256, split-K=2, bf16 partials -> ybuf16[rank*2+ks].
//   merge4:  out = sum of 4 bf16 partial buffers (fp32 accumulate).
// nt-major dispatch: co-resident blocks share the weight panel (L2-hot).
// ws layout (MiB), big path: [0,1) lists | [1,33) xb | [33,161) w1b |
//   [161,289) w3b (later ybuf16[4]) | [289,418) hbuf | [418,546) w2b
// ws layout (MiB), r12 path: w2b aliases w1b (convert after GU, serial).
// ---------------------------------------------------------------------------

constexpr int kTokens  = 8192;
constexpr int kHidden  = 2048;
constexpr int kInter   = 4096;
constexpr int kExperts = 8;

constexpr int BM = 128, BN = 128, BK = 64;
constexpr int MAX_MT = (2 * kTokens) / BM + kExperts;   // 136
constexpr int NTY = kInter / BK;                        // 64 K-tiles (Y)
constexpr int kSlotCap = 16512;                         // hbuf rows incl. slack
constexpr int GU_BLOCKS = (kInter / BN) * MAX_MT;       // 4352

typedef short bf16x8 __attribute__((ext_vector_type(8)));
typedef float f32x4  __attribute__((ext_vector_type(4)));
typedef unsigned int u32;

__device__ __forceinline__ unsigned short f2bf(float f) {
  union { float f; unsigned u; } v; v.f = f;
  unsigned r = v.u + 0x7FFFu + ((v.u >> 16) & 1u);  // RTNE
  return (unsigned short)(r >> 16);
}

__device__ __forceinline__ void gload16(const void* g, void* l) {
  __builtin_amdgcn_global_load_lds(
      (const __attribute__((address_space(1))) u32*)g,
      (__attribute__((address_space(3))) u32*)l, 16, 0, 0);
}

// ---------------------------- convert body (proven r2 layout) ---------------
__device__ __forceinline__ void convert_body(
    const float* __restrict__ src, unsigned short* __restrict__ dst,
    int lp, int lq, int K, long nchunks, int bid, int nblocks)
{
  long stride = (long)nblocks * 256;
  for (long g = bid * 256L + threadIdx.x; g < nchunks; g += stride) {
    int  l   = (int)(g & 1023);
    long blk = g >> 10;
    int  q   = (int)(blk & ((1 << lq) - 1));
    long ep  = blk >> lq;
    int  p   = (int)(ep & ((1 << lp) - 1));
    int  e   = (int)(ep >> lp);
    int r = l >> 3, cs = l & 7, c = cs ^ (r & 7);
    size_t soff = (((size_t)(e << lp) + p) * 128 + r) * (size_t)K + (size_t)q * 64 + c * 8;
    float4 v0 = *reinterpret_cast<const float4*>(src + soff);
    float4 v1 = *reinterpret_cast<const float4*>(src + soff + 4);
    uint4 o;
    o.x = (u32)f2bf(v0.x) | ((u32)f2bf(v0.y) << 16);
    o.y = (u32)f2bf(v0.z) | ((u32)f2bf(v0.w) << 16);
    o.z = (u32)f2bf(v1.x) | ((u32)f2bf(v1.y) << 16);
    o.w = (u32)f2bf(v1.z) | ((u32)f2bf(v1.w) << 16);
    *reinterpret_cast<uint4*>(dst + g * 8) = o;
  }
}

__global__ __launch_bounds__(256) void convert_w(
    const float* __restrict__ src, unsigned short* __restrict__ dst,
    int lp, int lq, int K, long nchunks)
{
  convert_body(src, dst, lp, lq, K, nchunks, blockIdx.x, gridDim.x);
}

// ------------- router body (idx packed t*2+rank) -------------
__device__ __forceinline__ void router_body(
    const float* __restrict__ x, const float* __restrict__ gate_w,
    unsigned short* __restrict__ xb, int* __restrict__ counts,
    int* __restrict__ list_idx, float* __restrict__ list_w, int bid)
{
  const int lane = threadIdx.x & 63;
  const int wave = threadIdx.x >> 6;
  const int t = bid * 4 + wave;

  float acc[kExperts];
#pragma unroll
  for (int e = 0; e < kExperts; ++e) acc[e] = 0.f;

  const float4* xrow = reinterpret_cast<const float4*>(x + (size_t)t * kHidden);
#pragma unroll
  for (int j = 0; j < 8; ++j) {
    float4 xv = xrow[j * 64 + lane];
    uint2 pk;
    pk.x = (u32)f2bf(xv.x) | ((u32)f2bf(xv.y) << 16);
    pk.y = (u32)f2bf(xv.z) | ((u32)f2bf(xv.w) << 16);
    *reinterpret_cast<uint2*>(xb + (size_t)t * kHidden + j * 256 + lane * 4) = pk;
#pragma unroll
    for (int e = 0; e < kExperts; ++e) {
      float4 gv = reinterpret_cast<const float4*>(gate_w + (size_t)e * kHidden)[j * 64 + lane];
      acc[e] += xv.x * gv.x + xv.y * gv.y + xv.z * gv.z + xv.w * gv.w;
    }
  }
#pragma unroll
  for (int e = 0; e < kExperts; ++e) {
#pragma unroll
    for (int m = 32; m >= 1; m >>= 1) acc[e] += __shfl_xor(acc[e], m);
  }
  if (lane == 0) {
    float mx = acc[0];
#pragma unroll
    for (int e = 1; e < kExperts; ++e) mx = fmaxf(mx, acc[e]);
    float p[kExperts]; float s = 0.f;
#pragma unroll
    for (int e = 0; e < kExperts; ++e) { p[e] = __expf(acc[e] - mx); s += p[e]; }
    float inv = 1.f / s;
    int i1 = 0; float v1 = p[0];
#pragma unroll
    for (int e = 1; e < kExperts; ++e) if (p[e] > v1) { v1 = p[e]; i1 = e; }
    int i2 = (i1 == 0) ? 1 : 0; float v2 = p[i2];
#pragma unroll
    for (int e = 0; e < kExperts; ++e) {
      if (e == i1 || e == i2) continue;
      if (p[e] > v2) { v2 = p[e]; i2 = e; }
    }
    int s1 = atomicAdd(&counts[i1], 1);
    list_idx[i1 * kTokens + s1] = t * 2 + 0;
    list_w [i1 * kTokens + s1] = v1 * inv;
    int s2 = atomicAdd(&counts[i2], 1);
    list_idx[i2 * kTokens + s2] = t * 2 + 1;
    list_w [i2 * kTokens + s2] = v2 * inv;
  }
}

// ------------- prep: router + w1 convert + w3 convert, one launch -----------
__global__ __launch_bounds__(256) void moe_prep(
    const float* __restrict__ x, const float* __restrict__ gate_w,
    unsigned short* __restrict__ xb, int* __restrict__ counts,
    int* __restrict__ list_idx, float* __restrict__ list_w,
    const float* __restrict__ w1, unsigned short* __restrict__ w1b,
    const float* __restrict__ w3, unsigned short* __restrict__ w3b,
    long nchunks)
{
  const int bid = blockIdx.x;
  if (bid < 2048) {
    router_body(x, gate_w, xb, counts, list_idx, list_w, bid);
  } else if (bid < 2048 + 4096) {
    convert_body(w1, w1b, 5, 5, kHidden, nchunks, bid - 2048, 4096);
  } else {
    convert_body(w3, w3b, 5, 5, kHidden, nchunks, bid - 6144, 4096);
  }
}

// standalone router (fallback path)
__global__ __launch_bounds__(256) void moe_router(
    const float* __restrict__ x, const float* __restrict__ gate_w,
    unsigned short* __restrict__ xb, int* __restrict__ counts,
    int* __restrict__ list_idx, float* __restrict__ list_w)
{
  router_body(x, gate_w, xb, counts, list_idx, list_w, blockIdx.x);
}

// ------------------- tile mapping helper -------------------
__device__ __forceinline__ bool map_tile(const int* __restrict__ counts, int mt,
                                         int& e, int& lm, int& sb, int& ne)
{
  int tb = 0; sb = 0;
  for (e = 0; e < kExperts; ++e) {
    ne = counts[e];
    int tiles = (ne + BM - 1) / BM;
    if (mt < tb + tiles) { lm = mt - tb; return true; }
    tb += tiles; sb += ne;
  }
  return false;
}

// --------------- GU GEMM body (byte-exact r2 structure, 625us) --------------
__device__ __forceinline__ void gu_body(
    const unsigned short* __restrict__ xb,
    const unsigned short* __restrict__ w1b, const unsigned short* __restrict__ w3b,
    const int* __restrict__ counts, const int* __restrict__ list_idx,
    unsigned short* __restrict__ hbuf, int bid)
{
  __shared__ unsigned short As [BM * BK];
  __shared__ unsigned short B1s[BN * BK];
  __shared__ unsigned short B3s[BN * BK];
  __shared__ int toks[BM];

  const int tid = threadIdx.x;
  const int nt  = bid / MAX_MT;
  const int mt  = bid % MAX_MT;

  int e, lm, sb, ne;
  if (!map_tile(counts, mt, e, lm, sb, ne)) return;
  const int row0 = lm * BM;

  if (tid < BM) {
    int lr = row0 + tid;
    toks[tid] = list_idx[e * kTokens + ((lr < ne) ? lr : 0)] >> 1;
  }
  __syncthreads();

  const int lane = tid & 63;
  const int w = tid >> 6;
  const int wr = w >> 1, wc = w & 1;

  const unsigned short* srcA[4];
  const unsigned short* srcB1[4];
  const unsigned short* srcB3[4];
  const size_t bbase = ((size_t)(e * (kInter / BN) + nt) * (kHidden / BK)) * 1024;
#pragma unroll
  for (int i = 0; i < 4; ++i) {
    int l = (w * 4 + i) * 64 + lane;
    int r = l >> 3, cs = l & 7, c = cs ^ (r & 7);
    srcA[i]  = xb  + (size_t)toks[r] * kHidden + c * 8;
    srcB1[i] = w1b + (bbase + l) * 8;
    srcB3[i] = w3b + (bbase + l) * 8;
  }

  f32x4 accG[4][4], accU[4][4];
  const f32x4 zero = {0.f, 0.f, 0.f, 0.f};
#pragma unroll
  for (int m = 0; m < 4; ++m)
#pragma unroll
    for (int n = 0; n < 4; ++n) { accG[m][n] = zero; accU[m][n] = zero; }

  for (int ks = 0; ks < kHidden / BK; ++ks) {
#pragma unroll
    for (int i = 0; i < 4; ++i) {
      gload16(srcA[i]  + ks * BK,            &As [(w * 4 + i) * 512]);
      gload16(srcB1[i] + (size_t)ks * 8192,  &B1s[(w * 4 + i) * 512]);
      gload16(srcB3[i] + (size_t)ks * 8192,  &B3s[(w * 4 + i) * 512]);
    }
    __syncthreads();
#pragma unroll
    for (int kk = 0; kk < 2; ++kk) {
      const int cq = kk * 4 + (lane >> 4);
      bf16x8 a[4], b1v[4], b3v[4];
#pragma unroll
      for (int m = 0; m < 4; ++m) {
        int row = wr * 64 + m * 16 + (lane & 15);
        a[m] = *reinterpret_cast<const bf16x8*>(&As[row * 64 + ((cq ^ (row & 7)) << 3)]);
      }
#pragma unroll
      for (int n = 0; n < 4; ++n) {
        int row = wc * 64 + n * 16 + (lane & 15);
        b1v[n] = *reinterpret_cast<const bf16x8*>(&B1s[row * 64 + ((cq ^ (row & 7)) << 3)]);
        b3v[n] = *reinterpret_cast<const bf16x8*>(&B3s[row * 64 + ((cq ^ (row & 7)) << 3)]);
      }
#pragma unroll
      for (int m = 0; m < 4; ++m)
#pragma unroll
        for (int n = 0; n < 4; ++n) {
          accG[m][n] = __builtin_amdgcn_mfma_f32_16x16x32_bf16(a[m], b1v[n], accG[m][n], 0, 0, 0);
          accU[m][n] = __builtin_amdgcn_mfma_f32_16x16x32_bf16(a[m], b3v[n], accU[m][n], 0, 0, 0);
        }
    }
    __syncthreads();
  }

#pragma unroll
  for (int m = 0; m < 4; ++m) {
#pragma unroll
    for (int r = 0; r < 4; ++r) {
      int rloc = wr * 64 + m * 16 + ((lane >> 4) * 4) + r;
      int lrow = row0 + rloc;
      if (lrow < ne) {
        size_t base = (size_t)(sb + lrow) * kInter + (size_t)nt * BN + wc * 64 + (lane & 15);
#pragma unroll
        for (int n = 0; n < 4; ++n) {
          float g = accG[m][n][r];
          float u = accU[m][n][r];
          float hv = (g / (1.f + __expf(-g))) * u;
          hbuf[base + n * 16] = f2bf(hv);
        }
      }
    }
  }
}

__global__ __launch_bounds__(256, 2) void moe_gu(
    const unsigned short* __restrict__ xb,
    const unsigned short* __restrict__ w1b, const unsigned short* __restrict__ w3b,
    const int* __restrict__ counts, const int* __restrict__ list_idx,
    unsigned short* __restrict__ hbuf)
{
  gu_body(xb, w1b, w3b, counts, list_idx, hbuf, blockIdx.x);
}

// GU fused with w2 convert: blocks >= GU_BLOCKS convert w2 into w2b (disjoint
// region) using GU's idle HBM bandwidth.
__global__ __launch_bounds__(256, 2) void moe_gu_fused(
    const unsigned short* __restrict__ xb,
    const unsigned short* __restrict__ w1b, const unsigned short* __restrict__ w3b,
    const int* __restrict__ counts, const int* __restrict__ list_idx,
    unsigned short* __restrict__ hbuf,
    const float* __restrict__ w2, unsigned short* __restrict__ w2b, long nch)
{
  const int bid = blockIdx.x;
  if (bid < GU_BLOCKS) {
    gu_body(xb, w1b, w3b, counts, list_idx, hbuf, bid);
  } else {
    convert_body(w2, w2b, 4, 6, kInter, nch, bid - GU_BLOCKS, 4096);
  }
}

// ------------- Y8: 128x256 + split-K=2, bf16 partial stores -------------
__global__ __launch_bounds__(512, 2) void moe_y8(
    const unsigned short* __restrict__ hbuf,
    const unsigned short* __restrict__ w2b,
    const int* __restrict__ counts, const int* __restrict__ list_idx,
    const float* __restrict__ list_w,
    unsigned short* __restrict__ ybuf16)
{
  __shared__ unsigned short As[8192];
  __shared__ unsigned short Bs[2][8192];
  __shared__ int   toks[BM];
  __shared__ float cofs[BM];
  __shared__ int   rnks[BM];

  const int tid = threadIdx.x;
  const int grp = blockIdx.x / MAX_MT;   // 0..15
  const int mt  = blockIdx.x % MAX_MT;
  const int ks  = grp >> 3;              // 0..1 K-half
  const int nt  = grp & 7;               // 0..7 col panel (256)

  int e, lm, sb, ne;
  if (!map_tile(counts, mt, e, lm, sb, ne)) return;
  const int row0 = lm * BM;

  if (tid < BM) {
    int lr = row0 + tid;
    bool v = lr < ne;
    int pk = v ? list_idx[e * kTokens + lr] : 0;
    toks[tid] = pk >> 1;
    rnks[tid] = pk & 1;
    cofs[tid] = v ? list_w[e * kTokens + lr] : 0.f;
  }
  __syncthreads();

  const int lane = tid & 63;
  const int w    = tid >> 6;
  const int wr   = w >> 2;   // 0..1
  const int wc   = w & 3;    // 0..3

  const unsigned short* srcA[2];
  int cOff[2];
#pragma unroll
  for (int j = 0; j < 2; ++j) {
    int l = (w * 2 + j) * 64 + lane;
    int r = l >> 3, c = (l & 7) ^ (r & 7);
    int rg = sb + row0 + r;
    if (rg > kSlotCap - 1) rg = kSlotCap - 1;
    srcA[j] = hbuf + (size_t)rg * kInter + c * 8;
    cOff[j] = l * 8;
  }
  const unsigned short* pB[2];
#pragma unroll
  for (int h = 0; h < 2; ++h)
    pB[h] = w2b + (size_t)(e * 16 + nt * 2 + h) * NTY * 8192;

  f32x4 acc[4][4];
  const f32x4 zero = {0.f, 0.f, 0.f, 0.f};
#pragma unroll
  for (int m = 0; m < 4; ++m)
#pragma unroll
    for (int n = 0; n < 4; ++n) acc[m][n] = zero;

  const int kt0 = ks * (NTY / 2);
  for (int kt = kt0; kt < kt0 + NTY / 2; ++kt) {
#pragma unroll
    for (int j = 0; j < 2; ++j) {
      gload16(srcA[j] + kt * BK, &As[(w * 2 + j) * 512]);
      gload16(pB[0] + (size_t)kt * 8192 + cOff[j], &Bs[0][(w * 2 + j) * 512]);
      gload16(pB[1] + (size_t)kt * 8192 + cOff[j], &Bs[1][(w * 2 + j) * 512]);
    }
    __syncthreads();
#pragma unroll
    for (int kk = 0; kk < 2; ++kk) {
      const int cq = kk * 4 + (lane >> 4);
      bf16x8 a[4], b[4];
#pragma unroll
      for (int m = 0; m < 4; ++m) {
        int row = wr * 64 + m * 16 + (lane & 15);
        a[m] = *reinterpret_cast<const bf16x8*>(&As[row * 64 + ((cq ^ (row & 7)) << 3)]);
      }
#pragma unroll
      for (int n = 0; n < 4; ++n) {
        int rr = wc * 64 + n * 16 + (lane & 15);
        int h = rr >> 7, rl = rr & 127;
        b[n] = *reinterpret_cast<const bf16x8*>(&Bs[h][rl * 64 + ((cq ^ (rl & 7)) << 3)]);
      }
#pragma unroll
      for (int m = 0; m < 4; ++m)
#pragma unroll
        for (int n = 0; n < 4; ++n)
          acc[m][n] = __builtin_amdgcn_mfma_f32_16x16x32_bf16(a[m], b[n], acc[m][n], 0, 0, 0);
    }
    __syncthreads();
  }

#pragma unroll
  for (int m = 0; m < 4; ++m) {
#pragma unroll
    for (int r = 0; r < 4; ++r) {
      int rloc = wr * 64 + m * 16 + ((lane >> 4) * 4) + r;
      if (row0 + rloc < ne) {
        float cf = cofs[rloc];
        size_t obase = ((size_t)(rnks[rloc] * 2 + ks) * kTokens + toks[rloc]) * kHidden
                     + (size_t)nt * 256 + wc * 64 + (lane & 15);
#pragma unroll
        for (int n = 0; n < 4; ++n)
          ybuf16[obase + n * 16] = f2bf(cf * acc[m][n][r]);
      }
    }
  }
}

// ---------------------------- merge4 ----------------------------
__global__ __launch_bounds__(256) void moe_merge4(
    const unsigned short* __restrict__ yb, float* __restrict__ out, long n8)
{
  const size_t bs = (size_t)kTokens * kHidden;
  long stride = (long)gridDim.x * blockDim.x;
  for (long i = blockIdx.x * (long)blockDim.x + threadIdx.x; i < n8; i += stride) {
    float s[8];
#pragma unroll
    for (int k = 0; k < 8; ++k) s[k] = 0.f;
#pragma unroll
    for (int b = 0; b < 4; ++b) {
      uint4 v = *reinterpret_cast<const uint4*>(yb + b * bs + (size_t)i * 8);
      const unsigned short* h = reinterpret_cast<const unsigned short*>(&v);
#pragma unroll
      for (int k = 0; k < 8; ++k) {
        union { unsigned u; float f; } cv; cv.u = (unsigned)h[k] << 16;
        s[k] += cv.f;
      }
    }
    float4 o0 = {s[0], s[1], s[2], s[3]};
    float4 o1 = {s[4], s[5], s[6], s[7]};
    *reinterpret_cast<float4*>(out + (size_t)i * 8)     = o0;
    *reinterpret_cast<float4*>(out + (size_t)i * 8 + 4) = o1;
  }
}

// ===================== fallback (fp32 on-the-fly, atomics) ==================
__global__ __launch_bounds__(256, 2) void moe_gu_f32(
    const unsigned short* __restrict__ xb,
    const float* __restrict__ w1, const float* __restrict__ w3,
    const int* __restrict__ counts, const int* __restrict__ list_idx,
    unsigned short* __restrict__ hbuf)
{
  __shared__ unsigned short As [BM * BK];
  __shared__ unsigned short B1s[BN * BK];
  __shared__ unsigned short B3s[BN * BK];
  __shared__ int toks[BM];

  const int tid = threadIdx.x;
  const int nt  = blockIdx.x / MAX_MT;
  const int mt  = blockIdx.x % MAX_MT;

  int e, lm, sb, ne;
  if (!map_tile(counts, mt, e, lm, sb, ne)) return;
  const int row0 = lm * BM;

  if (tid < BM) {
    int lr = row0 + tid;
    toks[tid] = list_idx[e * kTokens + ((lr < ne) ? lr : 0)] >> 1;
  }
  __syncthreads();

  const unsigned short* aptr[4];
#pragma unroll
  for (int i = 0; i < 4; ++i) {
    int chunk = i * 256 + tid;
    int r = chunk >> 3, c8 = chunk & 7;
    aptr[i] = xb + (size_t)toks[r] * kHidden + c8 * 8;
  }
  const float* w1e = w1 + (size_t)e * kInter * kHidden;
  const float* w3e = w3 + (size_t)e * kInter * kHidden;

  f32x4 accG[4][4], accU[4][4];
  const f32x4 zero = {0.f, 0.f, 0.f, 0.f};
#pragma unroll
  for (int m = 0; m < 4; ++m)
#pragma unroll
    for (int n = 0; n < 4; ++n) { accG[m][n] = zero; accU[m][n] = zero; }

  const int lane = tid & 63;
  const int wr = (tid >> 6) >> 1;
  const int wc = (tid >> 6) & 1;

  for (int k0 = 0; k0 < kHidden; k0 += BK) {
#pragma unroll
    for (int i = 0; i < 4; ++i) {
      int chunk = i * 256 + tid;
      uint4 v = *reinterpret_cast<const uint4*>(aptr[i] + k0);
      *reinterpret_cast<uint4*>(&As[chunk * 8]) = v;
    }
#pragma unroll
    for (int i = 0; i < 8; ++i) {
      int c = i * 256 + tid;
      int rowB = c >> 4, c16 = c & 15;
      size_t off = ((size_t)(nt * BN + rowB)) * kHidden + k0 + c16 * 4;
      float4 v1 = *reinterpret_cast<const float4*>(w1e + off);
      float4 v3 = *reinterpret_cast<const float4*>(w3e + off);
      uint2 p1, p3;
      p1.x = (u32)f2bf(v1.x) | ((u32)f2bf(v1.y) << 16);
      p1.y = (u32)f2bf(v1.z) | ((u32)f2bf(v1.w) << 16);
      p3.x = (u32)f2bf(v3.x) | ((u32)f2bf(v3.y) << 16);
      p3.y = (u32)f2bf(v3.z) | ((u32)f2bf(v3.w) << 16);
      *reinterpret_cast<uint2*>(&B1s[rowB * BK + c16 * 4]) = p1;
      *reinterpret_cast<uint2*>(&B3s[rowB * BK + c16 * 4]) = p3;
    }
    __syncthreads();
#pragma unroll
    for (int kk = 0; kk < 2; ++kk) {
      const int klo = kk * 32 + (lane >> 4) * 8;
      bf16x8 a[4], b1v[4], b3v[4];
#pragma unroll
      for (int m = 0; m < 4; ++m)
        a[m] = *reinterpret_cast<const bf16x8*>(&As[(wr * 64 + m * 16 + (lane & 15)) * BK + klo]);
#pragma unroll
      for (int n = 0; n < 4; ++n) {
        b1v[n] = *reinterpret_cast<const bf16x8*>(&B1s[(wc * 64 + n * 16 + (lane & 15)) * BK + klo]);
        b3v[n] = *reinterpret_cast<const bf16x8*>(&B3s[(wc * 64 + n * 16 + (lane & 15)) * BK + klo]);
      }
#pragma unroll
      for (int m = 0; m < 4; ++m)
#pragma unroll
        for (int n = 0; n < 4; ++n) {
          accG[m][n] = __builtin_amdgcn_mfma_f32_16x16x32_bf16(a[m], b1v[n], accG[m][n], 0, 0, 0);
          accU[m][n] = __builtin_amdgcn_mfma_f32_16x16x32_bf16(a[m], b3v[n], accU[m][n], 0, 0, 0);
        }
    }
    __syncthreads();
  }
#pragma unroll
  for (int m = 0; m < 4; ++m) {
#pragma unroll
    for (int r = 0; r < 4; ++r) {
      int rloc = wr * 64 + m * 16 + ((lane >> 4) * 4) + r;
      int lrow = row0 + rloc;
      if (lrow < ne) {
        size_t base = (size_t)(sb + lrow) * kInter + (size_t)nt * BN + wc * 64 + (lane & 15);
#pragma unroll
        for (int n = 0; n < 4; ++n) {
          float g = accG[m][n][r];
          float u = accU[m][n][r];
          hbuf[base + n * 16] = f2bf((g / (1.f + __expf(-g))) * u);
        }
      }
    }
  }
}

__global__ __launch_bounds__(256, 2) void moe_y_f32(
    const unsigned short* __restrict__ hbuf,
    const float* __restrict__ w2,
    const int* __restrict__ counts, const int* __restrict__ list_idx,
    const float* __restrict__ list_w,
    float* __restrict__ out)
{
  __shared__ unsigned short As[BM * BK];
  __shared__ unsigned short Bs[BN * BK];
  __shared__ int   toks[BM];
  __shared__ float cofs[BM];

  const int tid = threadIdx.x;
  const int nt  = blockIdx.x / MAX_MT;
  const int mt  = blockIdx.x % MAX_MT;

  int e, lm, sb, ne;
  if (!map_tile(counts, mt, e, lm, sb, ne)) return;
  const int row0 = lm * BM;

  if (tid < BM) {
    int lr = row0 + tid;
    bool v = lr < ne;
    toks[tid] = v ? (list_idx[e * kTokens + lr] >> 1) : 0;
    cofs[tid] = v ? list_w [e * kTokens + lr] : 0.f;
  }
  __syncthreads();

  const float* w2e = w2 + (size_t)e * kHidden * kInter;
  const unsigned short* arow = hbuf + (size_t)(sb + row0) * kInter;

  f32x4 acc[4][4];
  const f32x4 zero = {0.f, 0.f, 0.f, 0.f};
#pragma unroll
  for (int m = 0; m < 4; ++m)
#pragma unroll
    for (int n = 0; n < 4; ++n) acc[m][n] = zero;

  const int lane = tid & 63;
  const int wr = (tid >> 6) >> 1;
  const int wc = (tid >> 6) & 1;

  for (int k0 = 0; k0 < kInter; k0 += BK) {
#pragma unroll
    for (int i = 0; i < 4; ++i) {
      int chunk = i * 256 + tid;
      int r = chunk >> 3, c8 = chunk & 7;
      uint4 v = *reinterpret_cast<const uint4*>(arow + (size_t)r * kInter + k0 + c8 * 8);
      *reinterpret_cast<uint4*>(&As[chunk * 8]) = v;
    }
#pragma unroll
    for (int i = 0; i < 8; ++i) {
      int c = i * 256 + tid;
      int rowB = c >> 4, c16 = c & 15;
      size_t off = ((size_t)(nt * BN + rowB)) * kInter + k0 + c16 * 4;
      float4 v2 = *reinterpret_cast<const float4*>(w2e + off);
      uint2 p2;
      p2.x = (u32)f2bf(v2.x) | ((u32)f2bf(v2.y) << 16);
      p2.y = (u32)f2bf(v2.z) | ((u32)f2bf(v2.w) << 16);
      *reinterpret_cast<uint2*>(&Bs[rowB * BK + c16 * 4]) = p2;
    }
    __syncthreads();
#pragma unroll
    for (int kk = 0; kk < 2; ++kk) {
      const int klo = kk * 32 + (lane >> 4) * 8;
      bf16x8 a[4], b[4];
#pragma unroll
      for (int m = 0; m < 4; ++m)
        a[m] = *reinterpret_cast<const bf16x8*>(&As[(wr * 64 + m * 16 + (lane & 15)) * BK + klo]);
#pragma unroll
      for (int n = 0; n < 4; ++n)
        b[n] = *reinterpret_cast<const bf16x8*>(&Bs[(wc * 64 + n * 16 + (lane & 15)) * BK + klo]);
#pragma unroll
      for (int m = 0; m < 4; ++m)
#pragma unroll
        for (int n = 0; n < 4; ++n)
          acc[m][n] = __builtin_amdgcn_mfma_f32_16x16x32_bf16(a[m], b[n], acc[m][n], 0, 0, 0);
    }
    __syncthreads();
  }
#pragma unroll
  for (int m = 0; m < 4; ++m) {
#pragma unroll
    for (int r = 0; r < 4; ++r) {
      int rloc = wr * 64 + m * 16 + ((lane >> 4) * 4) + r;
      if (row0 + rloc < ne) {
        float cf = cofs[rloc];
        size_t obase = (size_t)toks[rloc] * kHidden + (size_t)nt * BN + wc * 64 + (lane & 15);
#pragma unroll
        for (int n = 0; n < 4; ++n)
          atomicAdd(&out[obase + n * 16], cf * acc[m][n][r]);
      }
    }
  }
}

// ---------------------------- host ----------------------------
extern "C" void kernel_launch(void* const* d_in, const int* in_sizes, int n_in,
                              void* d_out, int out_size, void* d_ws, size_t ws_size,
                              hipStream_t stream)
{
  const float* x      = (const float*)d_in[0];
  const float* gate_w = (const float*)d_in[1];
  const float* w1     = (const float*)d_in[2];
  const float* w2     = (const float*)d_in[3];
  const float* w3     = (const float*)d_in[4];
  float* out = (float*)d_out;

  char* ws = (char*)d_ws;
  const size_t MiB = 1ull << 20;
  int*   counts   = (int*)(ws);
  int*   list_idx = (int*)(ws + 1024);
  float* list_w   = (float*)(ws + 1024 + kExperts * kTokens * 4);

  hipMemsetAsync(counts, 0, 1024, stream);

  const long nch = (long)kExperts * 32 * 32 * 1024;  // same for all 3 weights

  if (ws_size >= 547 * MiB) {
    // big path: w2b disjoint -> w2 convert hidden inside GU launch
    unsigned short* xb     = (unsigned short*)(ws + 1 * MiB);
    unsigned short* w1b    = (unsigned short*)(ws + 33 * MiB);
    unsigned short* w3b    = (unsigned short*)(ws + 161 * MiB);
    unsigned short* hbuf   = (unsigned short*)(ws + 289 * MiB);
    unsigned short* w2b    = (unsigned short*)(ws + 418 * MiB);
    unsigned short* ybuf16 = (unsigned short*)(ws + 161 * MiB); // reuse w3b after GU

    moe_prep<<<10240, 256, 0, stream>>>(x, gate_w, xb, counts, list_idx, list_w,
                                        w1, w1b, w3, w3b, nch);
    moe_gu_fused<<<GU_BLOCKS + 4096, 256, 0, stream>>>(
        xb, w1b, w3b, counts, list_idx, hbuf, w2, w2b, nch);
    moe_y8<<<16 * MAX_MT, 512, 0, stream>>>(hbuf, w2b, counts, list_idx, list_w, ybuf16);
    moe_merge4<<<2048, 256, 0, stream>>>(ybuf16, out, (long)kTokens * kHidden / 8);
  } else if (ws_size >= 418 * MiB) {
    // r12 path: w2b aliases w1b, convert serialized after GU
    unsigned short* xb     = (unsigned short*)(ws + 1 * MiB);
    unsigned short* w1b    = (unsigned short*)(ws + 33 * MiB);
    unsigned short* w3b    = (unsigned short*)(ws + 161 * MiB);
    unsigned short* hbuf   = (unsigned short*)(ws + 289 * MiB);
    unsigned short* w2b    = w1b;
    unsigned short* ybuf16 = (unsigned short*)(ws + 161 * MiB);

    moe_prep<<<10240, 256, 0, stream>>>(x, gate_w, xb, counts, list_idx, list_w,
                                        w1, w1b, w3, w3b, nch);
    moe_gu<<<GU_BLOCKS, 256, 0, stream>>>(xb, w1b, w3b, counts, list_idx, hbuf);
    convert_w<<<4096, 256, 0, stream>>>(w2, w2b, 4, 6, kInter, nch);
    moe_y8<<<16 * MAX_MT, 512, 0, stream>>>(hbuf, w2b, counts, list_idx, list_w, ybuf16);
    moe_merge4<<<2048, 256, 0, stream>>>(ybuf16, out, (long)kTokens * kHidden / 8);
  } else {
    unsigned short* xb   = (unsigned short*)(ws + 1 * MiB);
    unsigned short* hbuf = (unsigned short*)(ws + 36 * MiB);
    hipMemsetAsync(out, 0, (size_t)kTokens * kHidden * sizeof(float), stream);
    moe_router<<<kTokens / 4, 256, 0, stream>>>(x, gate_w, xb, counts, list_idx, list_w);
    moe_gu_f32<<<(kInter / BN) * MAX_MT, 256, 0, stream>>>(xb, w1, w3, counts, list_idx, hbuf);
    moe_y_f32 <<<(kHidden / BN) * MAX_MT, 256, 0, stream>>>(hbuf, w2, counts, list_idx, list_w, out);
  }
}